// Round 9
// baseline (232.738 us; speedup 1.0000x reference)
//
#include <hip/hip_runtime.h>
#include <hip/hip_bf16.h>

typedef __bf16 bf16;
typedef __bf16 bf16x8 __attribute__((ext_vector_type(8)));
typedef __bf16 bf16x4v __attribute__((ext_vector_type(4)));
typedef float f32x4 __attribute__((ext_vector_type(4)));

#define D_MODEL 512
#define T_SEQ   4096
#define NH      8
#define DH      64
#define M_ROWS  8192   // B*T
#define VROW    8224   // 8192 + 32 pad tokens: V row stride 16448 B (non-pow2)
#define QK_SCALE 0.18033688011112042f   // 0.125 * log2(e), folded into Q

// async global->LDS, 16B per lane, linear LDS dest (wave base + lane*16)
__device__ __forceinline__ void gload16(const void* g, void* l) {
  __builtin_amdgcn_global_load_lds(
      (const __attribute__((address_space(1))) unsigned int*)g,
      (__attribute__((address_space(3))) unsigned int*)l, 16, 0, 0);
}

#define WAITV(N) asm volatile("s_waitcnt vmcnt(" #N ")" ::: "memory")
#define CFENCE   asm volatile("" ::: "memory")

// ---------------- kernel 0: dtype detector ----------------------------------
__global__ __launch_bounds__(64) void detect_dtype(const unsigned short* __restrict__ xr,
                                                   int* __restrict__ flag)
{
  int lane = threadIdx.x;
  int cnt = 0;
  for (int i = lane; i < 4096; i += 64) {
    unsigned short u = xr[i];
    int e = (u >> 7) & 0xFF;
    bool insane = (e >= 133) || (e > 0 && e <= 96) || (e == 0 && (u & 0x7F) != 0);
    cnt += insane ? 1 : 0;
  }
#pragma unroll
  for (int off = 32; off >= 1; off >>= 1) cnt += __shfl_xor(cnt, off);
  if (lane == 0) *flag = (cnt > 400) ? 1 : 0;   // 1 = inputs are fp32
}

// ---------------- kernel 0b: convert x to bf16 -------------------------------
__global__ __launch_bounds__(256) void convert_x(const void* __restrict__ xr,
                                                 const int* __restrict__ flag,
                                                 bf16* __restrict__ xb, int n)
{
  int i = (blockIdx.x * blockDim.x + threadIdx.x) * 4;
  if (i >= n) return;
  if (*flag) {
    float4 v = *(const float4*)((const float*)xr + i);
    __align__(8) bf16 o[4] = {(bf16)v.x, (bf16)v.y, (bf16)v.z, (bf16)v.w};
    *(uint2*)(xb + i) = *(uint2*)o;
  } else {
    *(uint2*)(xb + i) = *(const uint2*)((const bf16*)xr + i);
  }
}

// ---------------- kernel 0c: biases -> fp32, mask -> float shift -------------
__global__ __launch_bounds__(1024) void prep_aux(
    const void* b0, const void* b1, const void* b2, const void* b3,
    const int* __restrict__ mask,
    const int* __restrict__ flag, float* __restrict__ bf, float* __restrict__ mf)
{
  const void* ps[4] = {b0, b1, b2, b3};
  int fl = *flag;
  int g = blockIdx.x * 1024 + threadIdx.x;     // 0..8191
  if (g < 4 * D_MODEL) {
    int w = g >> 9, o = g & 511;
    bf[g] = fl ? ((const float*)ps[w])[o] : (float)((const bf16*)ps[w])[o];
  }
  mf[g] = mask[g] ? -16.0f : -1e30f;           // fixed-shift (exp2 domain) + mask
}

// ---------------- kernel 1: per-output-channel weight quant-dequant ----------
__global__ __launch_bounds__(256) void qdq_weights(
    const void* __restrict__ Wq, const void* __restrict__ Wk,
    const void* __restrict__ Wv, const void* __restrict__ Wo,
    const int* __restrict__ flag, bf16* __restrict__ out)
{
  int wave = threadIdx.x >> 6, lane = threadIdx.x & 63;
  int gid = blockIdx.x * 4 + wave;
  int w = gid >> 9, row = gid & 511;
  const void* W = (w == 0) ? Wq : (w == 1) ? Wk : (w == 2) ? Wv : Wo;
  int fl = *flag;
  float v[8]; float amax = 0.f;
#pragma unroll
  for (int i = 0; i < 8; i++) {
    int idx = row * D_MODEL + lane + 64 * i;
    v[i] = fl ? ((const float*)W)[idx] : (float)((const bf16*)W)[idx];
    amax = fmaxf(amax, fabsf(v[i]));
  }
#pragma unroll
  for (int off = 32; off >= 1; off >>= 1) amax = fmaxf(amax, __shfl_xor(amax, off));
  float s = fmaxf(amax / 127.0f, 1e-8f);
  bf16* dst = out + (size_t)gid * D_MODEL;
#pragma unroll
  for (int i = 0; i < 8; i++) {
    float q = rintf(v[i] / s);
    q = fminf(fmaxf(q, -127.f), 127.f);
    dst[lane + 64*i] = (bf16)(q * s);
  }
}

// ---------------- kernel 2a: fused QKV GEMM ----------------------------------
// Q/K written HEAD-MAJOR: Qh/Kh[(b*8+h)][t 0..4095][64] (contiguous per head)
// V written to VTP[ch 0..511][VROW tokens] (row stride 16448 B, non-pow2)
#define LDS_STRIDE 40
__global__ __launch_bounds__(256) void gemm_qkv(
    const bf16* __restrict__ A, const bf16* __restrict__ W,
    const float* __restrict__ bias,
    bf16* __restrict__ Qh, bf16* __restrict__ Kh, bf16* __restrict__ VTP)
{
  __shared__ __align__(16) bf16 As[128 * LDS_STRIDE];
  __shared__ __align__(16) bf16 Bs[128 * LDS_STRIDE];

  const int tid = threadIdx.x;
  const int wave = tid >> 6, lane = tid & 63;
  const int lr = lane & 15, quad = lane >> 4;
  const int wm = (wave >> 1) * 64, wn = (wave & 1) * 64;
  const int m0 = blockIdx.x * 128, n0 = blockIdx.y * 128;
  const int sec = blockIdx.y >> 2;   // 0=Q 1=K 2=V

  f32x4 acc[4][4];
#pragma unroll
  for (int i = 0; i < 4; i++)
#pragma unroll
    for (int j = 0; j < 4; j++) acc[i][j] = f32x4{0.f, 0.f, 0.f, 0.f};

  const int srow = tid >> 2;
  const int sseg = (tid & 3) * 8;

  for (int k0 = 0; k0 < D_MODEL; k0 += 32) {
#pragma unroll
    for (int i = 0; i < 2; i++) {
      int r = srow + i * 64;
      *(uint4*)&As[r * LDS_STRIDE + sseg] = *(const uint4*)(A + (size_t)(m0 + r) * D_MODEL + k0 + sseg);
      *(uint4*)&Bs[r * LDS_STRIDE + sseg] = *(const uint4*)(W + (size_t)(n0 + r) * D_MODEL + k0 + sseg);
    }
    __syncthreads();
    bf16x8 af[4], bfr[4];
#pragma unroll
    for (int mt = 0; mt < 4; mt++) af[mt]  = *(bf16x8*)&As[(wm + mt*16 + lr) * LDS_STRIDE + quad*8];
#pragma unroll
    for (int nt = 0; nt < 4; nt++) bfr[nt] = *(bf16x8*)&Bs[(wn + nt*16 + lr) * LDS_STRIDE + quad*8];
#pragma unroll
    for (int mt = 0; mt < 4; mt++)
#pragma unroll
      for (int nt = 0; nt < 4; nt++)
        acc[mt][nt] = __builtin_amdgcn_mfma_f32_16x16x32_bf16(af[mt], bfr[nt], acc[mt][nt], 0, 0, 0);
    __syncthreads();
  }

  const float scale = (sec == 0) ? QK_SCALE : 1.0f;
#pragma unroll
  for (int mt = 0; mt < 4; mt++) {
    int grow = m0 + wm + mt * 16 + quad * 4;
#pragma unroll
    for (int nt = 0; nt < 4; nt++) {
      int gcol = n0 + wn + nt * 16 + lr;
      float b = bias[gcol];
      if (sec == 2) {               // VTP[ch][token], packed x4, padded row
        bf16x4v pk;
#pragma unroll
        for (int r = 0; r < 4; r++) pk[r] = (bf16)(acc[mt][nt][r] + b);
        *(bf16x4v*)(VTP + (size_t)(gcol - 1024) * VROW + grow) = pk;
      } else {                      // head-major planes
        bf16* dst = (sec == 0) ? Qh : Kh;
        int c = gcol & 511;
        int hh = c >> 6, c64 = c & 63;
#pragma unroll
        for (int r = 0; r < 4; r++) {
          int row = grow + r;
          int bb = row >> 12, t = row & 4095;
          dst[((size_t)(bb * NH + hh) * T_SEQ + t) * DH + c64] =
              (bf16)((acc[mt][nt][r] + b) * scale);
        }
      }
    }
  }
}

// ---------------- kernel 2b: O-proj GEMM, 64x128, fp32 out + absmax ----------
__global__ __launch_bounds__(256) void gemm_o(
    const bf16* __restrict__ A, const bf16* __restrict__ W,
    const float* __restrict__ bias,
    float* __restrict__ Cf, unsigned int* __restrict__ amaxp)
{
  __shared__ __align__(16) bf16 As[64 * LDS_STRIDE];
  __shared__ __align__(16) bf16 Bs[128 * LDS_STRIDE];
  __shared__ float wred[4];

  const int tid = threadIdx.x;
  const int wave = tid >> 6, lane = tid & 63;
  const int lr = lane & 15, quad = lane >> 4;
  const int wm = (wave >> 1) * 32, wn = (wave & 1) * 64;
  const int m0 = blockIdx.x * 64, n0 = blockIdx.y * 128;

  f32x4 acc[2][4];
#pragma unroll
  for (int i = 0; i < 2; i++)
#pragma unroll
    for (int j = 0; j < 4; j++) acc[i][j] = f32x4{0.f, 0.f, 0.f, 0.f};

  const int srow = tid >> 2;
  const int sseg = (tid & 3) * 8;

  for (int k0 = 0; k0 < D_MODEL; k0 += 32) {
    *(uint4*)&As[srow * LDS_STRIDE + sseg] = *(const uint4*)(A + (size_t)(m0 + srow) * D_MODEL + k0 + sseg);
#pragma unroll
    for (int i = 0; i < 2; i++) {
      int r = srow + i * 64;
      *(uint4*)&Bs[r * LDS_STRIDE + sseg] = *(const uint4*)(W + (size_t)(n0 + r) * D_MODEL + k0 + sseg);
    }
    __syncthreads();
    bf16x8 af[2], bfr[4];
#pragma unroll
    for (int mt = 0; mt < 2; mt++) af[mt]  = *(bf16x8*)&As[(wm + mt*16 + lr) * LDS_STRIDE + quad*8];
#pragma unroll
    for (int nt = 0; nt < 4; nt++) bfr[nt] = *(bf16x8*)&Bs[(wn + nt*16 + lr) * LDS_STRIDE + quad*8];
#pragma unroll
    for (int mt = 0; mt < 2; mt++)
#pragma unroll
      for (int nt = 0; nt < 4; nt++)
        acc[mt][nt] = __builtin_amdgcn_mfma_f32_16x16x32_bf16(af[mt], bfr[nt], acc[mt][nt], 0, 0, 0);
    __syncthreads();
  }

  float lmax = 0.f;
#pragma unroll
  for (int mt = 0; mt < 2; mt++) {
    int grow = m0 + wm + mt * 16 + quad * 4;
#pragma unroll
    for (int nt = 0; nt < 4; nt++) {
      int gcol = n0 + wn + nt * 16 + lr;
      float b = bias[gcol];
#pragma unroll
      for (int r = 0; r < 4; r++) {
        float v = acc[mt][nt][r] + b;
        Cf[(size_t)(grow + r) * D_MODEL + gcol] = v;
        lmax = fmaxf(lmax, fabsf(v));
      }
    }
  }
#pragma unroll
  for (int off = 32; off >= 1; off >>= 1) lmax = fmaxf(lmax, __shfl_xor(lmax, off));
  if (lane == 0) wred[wave] = lmax;
  __syncthreads();
  if (tid == 0) {
    float m = fmaxf(fmaxf(wred[0], wred[1]), fmaxf(wred[2], wred[3]));
    atomicMax(amaxp, __float_as_uint(m));
  }
}

// ---------------- kernel 3: flash attention, QT=4 (2x arith intensity) -------
// 256 blocks x 256 thr (4 waves), 1 block/CU. Block owns (b,h) x 256 q-rows;
// each wave owns 64 q-rows (QT=4). R8 post-mortem: LDS read BW was the
// limiter (10.5 MB/CU = 63% of runtime at 85 B/cy; MfmaUtil only 34%).
// QT=4 doubles MFMA per staged byte: per chunk per wave 64 MFMA vs 20
// ds_read_b128 (was 16 vs 20) -> LDS read traffic per unit work HALVES,
// MFMA pipe becomes the limiter (~1242 cy/chunk/CU). Global staged traffic
// also halves (256 blocks x 1 MB). 1 wave/SIMD is acceptable here: the
// latencies on the critical path are ds_read (~120 cy, hidden by batched
// reads + MFMA trains), not global loads (3-deep DMA pipeline, counted
// vmcnt keeps them off-path). __launch_bounds__(256,1): VGPR headroom, no spill.
__global__ __launch_bounds__(256, 1) void attn(
    const bf16* __restrict__ Q, const bf16* __restrict__ K, const bf16* __restrict__ VT,
    const float* __restrict__ maskf, bf16* __restrict__ ctx)
{
  __shared__ __align__(16) bf16 Ks[3][64 * 64];          // 24 KB
  __shared__ __align__(16) bf16 Vs[3][64 * 64];          // 24 KB
  __shared__ __align__(16) float Mf[T_SEQ];              // 16 KB  (64 KB total)

  const int tid = threadIdx.x;
  const int wave = tid >> 6, lane = tid & 63;
  const int lr = lane & 15, quad = lane >> 4;
  // XCD swizzle: linear%8 = XCD -> 2 bh per XCD, all q-blocks of a bh on one XCD
  const int i = blockIdx.x;
  const int bh = (i & 7) * 2 + ((i >> 3) & 1);
  const int qb = i >> 4;                    // 0..15
  const int b = bh >> 3, h = bh & 7;
  const int q0 = qb * 256 + wave * 64;

  const bf16* Qb = Q + (size_t)bh * T_SEQ * DH;                 // Qh[bh][t][64]
  const bf16* Kb = K + (size_t)bh * T_SEQ * DH;                 // Kh[bh][t][64]
  const bf16* Vb = VT + (size_t)(h * DH) * VROW + (size_t)b * T_SEQ; // VTP rows
  const float* mb = maskf + b * T_SEQ;

  const int phase = (qb * 4) & 63;          // de-phase blocks of same bh

  // per-thread staging bases (constant across chunks)
  // slot s = ii*256+tid; LDS row = s>>3, 16B-slot sl = s&7 (XOR pre-swizzle)
  // K rows PERMUTED (R7): LDS row (kt,m) holds key (m>>2)*8+(kt&1)*4+(m&3)+(kt>>1)*32
  const bf16* kSrc[2]; const bf16* vSrc[2];
#pragma unroll
  for (int ii = 0; ii < 2; ii++) {
    int s = ii * 256 + tid, row = s >> 3, sl = s & 7;
    int kt = row >> 4, m = row & 15;
    int keym = ((m >> 2) << 3) + ((kt & 1) << 2) + (m & 3) + ((kt >> 1) << 5);
    kSrc[ii] = Kb + (size_t)keym * DH + ((sl ^ (row & 7)) << 3);
    vSrc[ii] = Vb + (size_t)row * VROW + ((sl ^ (row & 7)) << 3);
  }

  // ---- prologue ----
  // 1) Q frags via regular loads, then drain so vmcnt ledger = stage DMAs only
  bf16x8 qf[4][2];       // Q as B-frags: B[k=dh][n=q=lr]
#pragma unroll
  for (int qt = 0; qt < 4; qt++) {
    const bf16* rq = Qb + (size_t)(q0 + qt * 16 + lr) * DH;
    qf[qt][0] = *(const bf16x8*)(rq + quad * 8);
    qf[qt][1] = *(const bf16x8*)(rq + 32 + quad * 8);
  }
  WAITV(0);

  // 2) mask DMA (4 ops) then chunks 0,1,2 (4 ops each) -> 16 outstanding
#pragma unroll
  for (int ii = 0; ii < 4; ii++) {
    int g = ii * 256 + tid;
    gload16(mb + g * 4, &Mf[g * 4]);
  }
#pragma unroll
  for (int d = 0; d < 3; d++) {
    int kb = ((phase + d) & 63) * 64;
#pragma unroll
    for (int ii = 0; ii < 2; ii++) {
      int s = ii * 256 + tid;
      gload16(kSrc[ii] + (size_t)kb * DH, &Ks[d][s * 8]);
      gload16(vSrc[ii] + kb, &Vs[d][s * 8]);
    }
  }

  f32x4 O[4][4];         // O[qt][nt]: C-layout row=quad*4+r (q), col=lr (dh)
#pragma unroll
  for (int a = 0; a < 4; a++)
#pragma unroll
    for (int c = 0; c < 4; c++) O[a][c] = f32x4{0.f, 0.f, 0.f, 0.f};
  float lacc[4] = {0.f, 0.f, 0.f, 0.f};

  WAITV(8);              // retires mask + chunk0; chunks 1,2 stay in flight
  __builtin_amdgcn_s_barrier();
  CFENCE;

  int cur = 0, cc = phase;
  for (int j = 0; j < 64; j++) {
    // mask C-init from LDS, PERMUTED to match K-row staging
    f32x4 mk[4];
#pragma unroll
    for (int kt = 0; kt < 4; kt++)
      mk[kt] = *(const f32x4*)&Mf[cc * 64 + ((kt >> 1) << 5) + (quad << 3) + ((kt & 1) << 2)];

    // K A-frags from swizzled LDS
    bf16x8 kr[4][2];
#pragma unroll
    for (int kt = 0; kt < 4; kt++)
#pragma unroll
      for (int kh = 0; kh < 2; kh++)
        kr[kt][kh] = *(const bf16x8*)&Ks[cur][(kt * 16 + lr) * 64 +
                                             (((kh * 4 + quad) ^ (lr & 7)) << 3)];

    // S^T = K.Q^T (permuted keys); exp2 -> in-register PV A-frags
    bf16x8 pfa[4][2];
#pragma unroll
    for (int qt = 0; qt < 4; qt++) {
      f32x4 z[4];
#pragma unroll
      for (int kt = 0; kt < 4; kt++) {
        f32x4 t = mk[kt];
        t = __builtin_amdgcn_mfma_f32_16x16x32_bf16(kr[kt][0], qf[qt][0], t, 0, 0, 0);
        t = __builtin_amdgcn_mfma_f32_16x16x32_bf16(kr[kt][1], qf[qt][1], t, 0, 0, 0);
        z[kt] = t;
      }
      float la = lacc[qt];
#pragma unroll
      for (int kt = 0; kt < 4; kt++) {
#pragma unroll
        for (int r = 0; r < 4; r++) {
          float p = __builtin_amdgcn_exp2f(z[kt][r]);
          la += p;
          pfa[qt][kt >> 1][((kt & 1) << 2) + r] = (bf16)p;
        }
      }
      lacc[qt] = la;
    }

    // V B-frags from swizzled LDS
    bf16x8 vr[4][2];
#pragma unroll
    for (int nt = 0; nt < 4; nt++)
#pragma unroll
      for (int ks = 0; ks < 2; ks++)
        vr[nt][ks] = *(const bf16x8*)&Vs[cur][(nt * 16 + lr) * 64 +
                                             (((ks * 4 + quad) ^ (lr & 7)) << 3)];

    // PV accumulate (pfa is natural-key-order A-frag)
#pragma unroll
    for (int nt = 0; nt < 4; nt++)
#pragma unroll
      for (int qt = 0; qt < 4; qt++) {
        O[qt][nt] = __builtin_amdgcn_mfma_f32_16x16x32_bf16(pfa[qt][0], vr[nt][0], O[qt][nt], 0, 0, 0);
        O[qt][nt] = __builtin_amdgcn_mfma_f32_16x16x32_bf16(pfa[qt][1], vr[nt][1], O[qt][nt], 0, 0, 0);
      }

    if (j < 63) {
      __builtin_amdgcn_s_barrier();   // all waves done reading buf[cur]
      CFENCE;
      if (j < 61) {                   // issue chunk cc+3 into buf[cur]
        int kb = ((cc + 3) & 63) * 64;
#pragma unroll
        for (int ii = 0; ii < 2; ii++) {
          int s = ii * 256 + tid;
          gload16(kSrc[ii] + (size_t)kb * DH, &Ks[cur][s * 8]);
          gload16(vSrc[ii] + kb, &Vs[cur][s * 8]);
        }
        WAITV(8);                     // retires chunk j+1; j+2,j+3 in flight
      } else if (j == 61) {
        WAITV(4);                     // retires chunk 62; 63 in flight
      } else {
        WAITV(0);                     // retires chunk 63
      }
      __builtin_amdgcn_s_barrier();   // chunk j+1 visible to all waves
      CFENCE;
    }
    cur = (cur == 2) ? 0 : cur + 1;
    cc = (cc + 1) & 63;
  }

  // epilogue: normalize + store (each wave owns its 64 q-rows; no combine)
#pragma unroll
  for (int qt = 0; qt < 4; qt++) {
    float ls = lacc[qt];
    ls += __shfl_xor(ls, 16);
    ls += __shfl_xor(ls, 32);
    float linv = 1.0f / ls;
    float lO[4];
#pragma unroll
    for (int r = 0; r < 4; r++) lO[r] = __shfl(linv, quad * 4 + r);
#pragma unroll
    for (int nt = 0; nt < 4; nt++)
#pragma unroll
      for (int r = 0; r < 4; r++) {
        size_t row = (size_t)(b * T_SEQ + q0 + qt * 16 + quad * 4 + r);
        ctx[row * D_MODEL + h * DH + nt * 16 + lr] = (bf16)(O[qt][nt][r] * lO[r]);
      }
  }
}

// ---------------- kernel 4: per-tensor activation quant-dequant --------------
__global__ __launch_bounds__(256) void act_qdq(
    const float* __restrict__ pre, const unsigned int* __restrict__ amaxp,
    const int* __restrict__ flag, void* __restrict__ outv, int n)
{
  int i = (blockIdx.x * blockDim.x + threadIdx.x) * 4;
  if (i >= n) return;
  float s = fmaxf(__uint_as_float(*amaxp) / 127.0f, 1e-8f);
  float4 v = *(const float4*)(pre + i);
  float o[4] = {v.x, v.y, v.z, v.w};
#pragma unroll
  for (int r = 0; r < 4; r++) {
    float q = rintf(o[r] / s);
    q = fminf(fmaxf(q, -127.f), 127.f);
    o[r] = q * s;
  }
  if (*flag) {
    *(float4*)((float*)outv + i) = make_float4(o[0], o[1], o[2], o[3]);
  } else {
    __align__(8) bf16 ob[4] = {(bf16)o[0], (bf16)o[1], (bf16)o[2], (bf16)o[3]};
    *(uint2*)((bf16*)outv + i) = *(uint2*)ob;
  }
}

// ---------------- launch -----------------------------------------------------
extern "C" void kernel_launch(void* const* d_in, const int* in_sizes, int n_in,
                              void* d_out, int out_size, void* d_ws, size_t ws_size,
                              hipStream_t stream) {
  const void* x    = d_in[0];
  const int*  mask = (const int*)d_in[1];
  const void* Wq = d_in[2]; const void* bq = d_in[3];
  const void* Wk = d_in[4]; const void* bk = d_in[5];
  const void* Wv = d_in[6]; const void* bv = d_in[7];
  const void* Wo = d_in[8]; const void* bo = d_in[9];

  char* ws = (char*)d_ws;
  int*  flag  = (int*)(ws + 0);
  unsigned int* amax = (unsigned int*)(ws + 64);
  float* biasf = (float*)(ws + 1024);                 // 8 KB
  float* maskf = (float*)(ws + 16384);                // 32 KB
  bf16* Wt  = (bf16*)(ws + 65536);                    // 2 MB
  bf16* xb  = (bf16*)(ws + 4194304);                  // 8 MB
  bf16* Qm  = (bf16*)(ws + 12582912);                 // 8 MB head-major planes
  bf16* Km  = (bf16*)(ws + 20971520);                 // 8 MB head-major planes
  bf16* VT  = (bf16*)(ws + 29360128);                 // 8.42 MB: VTP[ch][8224]
  bf16* Cm  = (bf16*)(ws + 4194304);                  // overlays xb
  float* pre = (float*)(ws + 12582912);               // overlays Qm+Km

  hipMemsetAsync(amax, 0, 4, stream);
  detect_dtype<<<1, 64, 0, stream>>>((const unsigned short*)x, flag);
  convert_x<<<4096, 256, 0, stream>>>(x, flag, xb, M_ROWS * D_MODEL);
  prep_aux<<<8, 1024, 0, stream>>>(bq, bk, bv, bo, mask, flag, biasf, maskf);
  qdq_weights<<<512, 256, 0, stream>>>(Wq, Wk, Wv, Wo, flag, Wt);
  gemm_qkv<<<dim3(64, 12), 256, 0, stream>>>(xb, Wt, biasf, Qm, Km, VT);
  attn<<<256, 256, 0, stream>>>(Qm, Km, VT, maskf, Cm);
  gemm_o<<<dim3(128, 4), 256, 0, stream>>>(Cm, Wt + 3*262144, biasf + 1536, pre, amax);
  act_qdq<<<4096, 256, 0, stream>>>(pre, amax, flag, d_out, M_ROWS * D_MODEL);
}

// Round 10
// 222.463 us; speedup vs baseline: 1.0462x; 1.0462x over previous
//
#include <hip/hip_runtime.h>
#include <hip/hip_bf16.h>

typedef __bf16 bf16;
typedef __bf16 bf16x8 __attribute__((ext_vector_type(8)));
typedef __bf16 bf16x4v __attribute__((ext_vector_type(4)));
typedef float f32x4 __attribute__((ext_vector_type(4)));

#define D_MODEL 512
#define T_SEQ   4096
#define NH      8
#define DH      64
#define M_ROWS  8192   // B*T
#define VROW    8224   // 8192 + 32 pad tokens: V row stride 16448 B (non-pow2)
#define QK_SCALE 0.18033688011112042f   // 0.125 * log2(e), folded into Q

// async global->LDS, 16B per lane, linear LDS dest (wave base + lane*16)
__device__ __forceinline__ void gload16(const void* g, void* l) {
  __builtin_amdgcn_global_load_lds(
      (const __attribute__((address_space(1))) unsigned int*)g,
      (__attribute__((address_space(3))) unsigned int*)l, 16, 0, 0);
}

#define WAITV(N) asm volatile("s_waitcnt vmcnt(" #N ")" ::: "memory")
#define CFENCE   asm volatile("" ::: "memory")

// ---------------- kernel 0: dtype detector ----------------------------------
__global__ __launch_bounds__(64) void detect_dtype(const unsigned short* __restrict__ xr,
                                                   int* __restrict__ flag)
{
  int lane = threadIdx.x;
  int cnt = 0;
  for (int i = lane; i < 4096; i += 64) {
    unsigned short u = xr[i];
    int e = (u >> 7) & 0xFF;
    bool insane = (e >= 133) || (e > 0 && e <= 96) || (e == 0 && (u & 0x7F) != 0);
    cnt += insane ? 1 : 0;
  }
#pragma unroll
  for (int off = 32; off >= 1; off >>= 1) cnt += __shfl_xor(cnt, off);
  if (lane == 0) *flag = (cnt > 400) ? 1 : 0;   // 1 = inputs are fp32
}

// ---------------- kernel 0b: convert x to bf16 -------------------------------
__global__ __launch_bounds__(256) void convert_x(const void* __restrict__ xr,
                                                 const int* __restrict__ flag,
                                                 bf16* __restrict__ xb, int n)
{
  int i = (blockIdx.x * blockDim.x + threadIdx.x) * 4;
  if (i >= n) return;
  if (*flag) {
    float4 v = *(const float4*)((const float*)xr + i);
    __align__(8) bf16 o[4] = {(bf16)v.x, (bf16)v.y, (bf16)v.z, (bf16)v.w};
    *(uint2*)(xb + i) = *(uint2*)o;
  } else {
    *(uint2*)(xb + i) = *(const uint2*)((const bf16*)xr + i);
  }
}

// ---------------- kernel 0c: biases -> fp32, mask -> float shift -------------
__global__ __launch_bounds__(1024) void prep_aux(
    const void* b0, const void* b1, const void* b2, const void* b3,
    const int* __restrict__ mask,
    const int* __restrict__ flag, float* __restrict__ bf, float* __restrict__ mf)
{
  const void* ps[4] = {b0, b1, b2, b3};
  int fl = *flag;
  int g = blockIdx.x * 1024 + threadIdx.x;     // 0..8191
  if (g < 4 * D_MODEL) {
    int w = g >> 9, o = g & 511;
    bf[g] = fl ? ((const float*)ps[w])[o] : (float)((const bf16*)ps[w])[o];
  }
  mf[g] = mask[g] ? -16.0f : -1e30f;           // fixed-shift (exp2 domain) + mask
}

// ---------------- kernel 1: per-output-channel weight quant-dequant ----------
__global__ __launch_bounds__(256) void qdq_weights(
    const void* __restrict__ Wq, const void* __restrict__ Wk,
    const void* __restrict__ Wv, const void* __restrict__ Wo,
    const int* __restrict__ flag, bf16* __restrict__ out)
{
  int wave = threadIdx.x >> 6, lane = threadIdx.x & 63;
  int gid = blockIdx.x * 4 + wave;
  int w = gid >> 9, row = gid & 511;
  const void* W = (w == 0) ? Wq : (w == 1) ? Wk : (w == 2) ? Wv : Wo;
  int fl = *flag;
  float v[8]; float amax = 0.f;
#pragma unroll
  for (int i = 0; i < 8; i++) {
    int idx = row * D_MODEL + lane + 64 * i;
    v[i] = fl ? ((const float*)W)[idx] : (float)((const bf16*)W)[idx];
    amax = fmaxf(amax, fabsf(v[i]));
  }
#pragma unroll
  for (int off = 32; off >= 1; off >>= 1) amax = fmaxf(amax, __shfl_xor(amax, off));
  float s = fmaxf(amax / 127.0f, 1e-8f);
  bf16* dst = out + (size_t)gid * D_MODEL;
#pragma unroll
  for (int i = 0; i < 8; i++) {
    float q = rintf(v[i] / s);
    q = fminf(fmaxf(q, -127.f), 127.f);
    dst[lane + 64*i] = (bf16)(q * s);
  }
}

// ---------------- kernel 2a: fused QKV GEMM ----------------------------------
// Q/K written HEAD-MAJOR: Qh/Kh[(b*8+h)][t 0..4095][64] (contiguous per head)
// V written to VTP[ch 0..511][VROW tokens] (row stride 16448 B, non-pow2)
#define LDS_STRIDE 40
__global__ __launch_bounds__(256) void gemm_qkv(
    const bf16* __restrict__ A, const bf16* __restrict__ W,
    const float* __restrict__ bias,
    bf16* __restrict__ Qh, bf16* __restrict__ Kh, bf16* __restrict__ VTP)
{
  __shared__ __align__(16) bf16 As[128 * LDS_STRIDE];
  __shared__ __align__(16) bf16 Bs[128 * LDS_STRIDE];

  const int tid = threadIdx.x;
  const int wave = tid >> 6, lane = tid & 63;
  const int lr = lane & 15, quad = lane >> 4;
  const int wm = (wave >> 1) * 64, wn = (wave & 1) * 64;
  const int m0 = blockIdx.x * 128, n0 = blockIdx.y * 128;
  const int sec = blockIdx.y >> 2;   // 0=Q 1=K 2=V

  f32x4 acc[4][4];
#pragma unroll
  for (int i = 0; i < 4; i++)
#pragma unroll
    for (int j = 0; j < 4; j++) acc[i][j] = f32x4{0.f, 0.f, 0.f, 0.f};

  const int srow = tid >> 2;
  const int sseg = (tid & 3) * 8;

  for (int k0 = 0; k0 < D_MODEL; k0 += 32) {
#pragma unroll
    for (int i = 0; i < 2; i++) {
      int r = srow + i * 64;
      *(uint4*)&As[r * LDS_STRIDE + sseg] = *(const uint4*)(A + (size_t)(m0 + r) * D_MODEL + k0 + sseg);
      *(uint4*)&Bs[r * LDS_STRIDE + sseg] = *(const uint4*)(W + (size_t)(n0 + r) * D_MODEL + k0 + sseg);
    }
    __syncthreads();
    bf16x8 af[4], bfr[4];
#pragma unroll
    for (int mt = 0; mt < 4; mt++) af[mt]  = *(bf16x8*)&As[(wm + mt*16 + lr) * LDS_STRIDE + quad*8];
#pragma unroll
    for (int nt = 0; nt < 4; nt++) bfr[nt] = *(bf16x8*)&Bs[(wn + nt*16 + lr) * LDS_STRIDE + quad*8];
#pragma unroll
    for (int mt = 0; mt < 4; mt++)
#pragma unroll
      for (int nt = 0; nt < 4; nt++)
        acc[mt][nt] = __builtin_amdgcn_mfma_f32_16x16x32_bf16(af[mt], bfr[nt], acc[mt][nt], 0, 0, 0);
    __syncthreads();
  }

  const float scale = (sec == 0) ? QK_SCALE : 1.0f;
#pragma unroll
  for (int mt = 0; mt < 4; mt++) {
    int grow = m0 + wm + mt * 16 + quad * 4;
#pragma unroll
    for (int nt = 0; nt < 4; nt++) {
      int gcol = n0 + wn + nt * 16 + lr;
      float b = bias[gcol];
      if (sec == 2) {               // VTP[ch][token], packed x4, padded row
        bf16x4v pk;
#pragma unroll
        for (int r = 0; r < 4; r++) pk[r] = (bf16)(acc[mt][nt][r] + b);
        *(bf16x4v*)(VTP + (size_t)(gcol - 1024) * VROW + grow) = pk;
      } else {                      // head-major planes
        bf16* dst = (sec == 0) ? Qh : Kh;
        int c = gcol & 511;
        int hh = c >> 6, c64 = c & 63;
#pragma unroll
        for (int r = 0; r < 4; r++) {
          int row = grow + r;
          int bb = row >> 12, t = row & 4095;
          dst[((size_t)(bb * NH + hh) * T_SEQ + t) * DH + c64] =
              (bf16)((acc[mt][nt][r] + b) * scale);
        }
      }
    }
  }
}

// ---------------- kernel 2b: O-proj GEMM, 64x128, fp32 out + absmax ----------
__global__ __launch_bounds__(256) void gemm_o(
    const bf16* __restrict__ A, const bf16* __restrict__ W,
    const float* __restrict__ bias,
    float* __restrict__ Cf, unsigned int* __restrict__ amaxp)
{
  __shared__ __align__(16) bf16 As[64 * LDS_STRIDE];
  __shared__ __align__(16) bf16 Bs[128 * LDS_STRIDE];
  __shared__ float wred[4];

  const int tid = threadIdx.x;
  const int wave = tid >> 6, lane = tid & 63;
  const int lr = lane & 15, quad = lane >> 4;
  const int wm = (wave >> 1) * 32, wn = (wave & 1) * 64;
  const int m0 = blockIdx.x * 64, n0 = blockIdx.y * 128;

  f32x4 acc[2][4];
#pragma unroll
  for (int i = 0; i < 2; i++)
#pragma unroll
    for (int j = 0; j < 4; j++) acc[i][j] = f32x4{0.f, 0.f, 0.f, 0.f};

  const int srow = tid >> 2;
  const int sseg = (tid & 3) * 8;

  for (int k0 = 0; k0 < D_MODEL; k0 += 32) {
    *(uint4*)&As[srow * LDS_STRIDE + sseg] = *(const uint4*)(A + (size_t)(m0 + srow) * D_MODEL + k0 + sseg);
#pragma unroll
    for (int i = 0; i < 2; i++) {
      int r = srow + i * 64;
      *(uint4*)&Bs[r * LDS_STRIDE + sseg] = *(const uint4*)(W + (size_t)(n0 + r) * D_MODEL + k0 + sseg);
    }
    __syncthreads();
    bf16x8 af[2], bfr[4];
#pragma unroll
    for (int mt = 0; mt < 2; mt++) af[mt]  = *(bf16x8*)&As[(wm + mt*16 + lr) * LDS_STRIDE + quad*8];
#pragma unroll
    for (int nt = 0; nt < 4; nt++) bfr[nt] = *(bf16x8*)&Bs[(wn + nt*16 + lr) * LDS_STRIDE + quad*8];
#pragma unroll
    for (int mt = 0; mt < 2; mt++)
#pragma unroll
      for (int nt = 0; nt < 4; nt++)
        acc[mt][nt] = __builtin_amdgcn_mfma_f32_16x16x32_bf16(af[mt], bfr[nt], acc[mt][nt], 0, 0, 0);
    __syncthreads();
  }

  float lmax = 0.f;
#pragma unroll
  for (int mt = 0; mt < 2; mt++) {
    int grow = m0 + wm + mt * 16 + quad * 4;
#pragma unroll
    for (int nt = 0; nt < 4; nt++) {
      int gcol = n0 + wn + nt * 16 + lr;
      float b = bias[gcol];
#pragma unroll
      for (int r = 0; r < 4; r++) {
        float v = acc[mt][nt][r] + b;
        Cf[(size_t)(grow + r) * D_MODEL + gcol] = v;
        lmax = fmaxf(lmax, fabsf(v));
      }
    }
  }
#pragma unroll
  for (int off = 32; off >= 1; off >>= 1) lmax = fmaxf(lmax, __shfl_xor(lmax, off));
  if (lane == 0) wred[wave] = lmax;
  __syncthreads();
  if (tid == 0) {
    float m = fmaxf(fmaxf(wred[0], wred[1]), fmaxf(wred[2], wred[3]));
    atomicMax(amaxp, __float_as_uint(m));
  }
}

// ---------------- kernel 3: flash attention, l-via-MFMA (R8 base) ------------
// 512 blocks x 256 thr (4 waves), 2 blocks/CU (R9 falsified QT=4@1wave/SIMD:
// total q-rows fix waves*QT, and <2 waves/SIMD exposes the serial chain).
// R10 change: the row-sum l = P.1 is computed ON THE MATRIX PIPE via a ones
// B-frag (4 extra MFMA/wave-chunk) instead of 64 sequential dependent
// v_add_f32 (~128-256cy of pure dep-chain latency per chunk, the largest
// avoidable member of the critical path). Bonus: MFMA C-layout leaves each
// lane holding l for exactly the rows it stores -> epilogue shuffles gone.
// T5 setprio(1) around MFMA clusters (2 independent blocks/CU to arbitrate).
__global__ __launch_bounds__(256, 2) void attn(
    const bf16* __restrict__ Q, const bf16* __restrict__ K, const bf16* __restrict__ VT,
    const float* __restrict__ maskf, bf16* __restrict__ ctx)
{
  __shared__ __align__(16) bf16 Ks[3][64 * 64];          // 24 KB
  __shared__ __align__(16) bf16 Vs[3][64 * 64];          // 24 KB
  __shared__ __align__(16) float Mf[T_SEQ];              // 16 KB  (64 KB total)

  const int tid = threadIdx.x;
  const int wave = tid >> 6, lane = tid & 63;
  const int lr = lane & 15, quad = lane >> 4;
  // XCD swizzle: linear%8 = XCD -> 2 bh per XCD, all q-blocks of a bh on one XCD
  const int i = blockIdx.x;
  const int bh = (i & 7) * 2 + ((i >> 3) & 1);
  const int qb = i >> 4;                    // 0..31
  const int b = bh >> 3, h = bh & 7;
  const int q0 = qb * 128 + wave * 32;

  const bf16* Qb = Q + (size_t)bh * T_SEQ * DH;                 // Qh[bh][t][64]
  const bf16* Kb = K + (size_t)bh * T_SEQ * DH;                 // Kh[bh][t][64]
  const bf16* Vb = VT + (size_t)(h * DH) * VROW + (size_t)b * T_SEQ; // VTP rows
  const float* mb = maskf + b * T_SEQ;

  const int phase = (qb * 2) & 63;          // de-phase blocks of same bh

  // per-thread staging bases (constant across chunks)
  // slot s = ii*256+tid; LDS row = s>>3, 16B-slot sl = s&7 (XOR pre-swizzle)
  // K rows PERMUTED (R7): LDS row (kt,m) holds key (m>>2)*8+(kt&1)*4+(m&3)+(kt>>1)*32
  const bf16* kSrc[2]; const bf16* vSrc[2];
#pragma unroll
  for (int ii = 0; ii < 2; ii++) {
    int s = ii * 256 + tid, row = s >> 3, sl = s & 7;
    int kt = row >> 4, m = row & 15;
    int keym = ((m >> 2) << 3) + ((kt & 1) << 2) + (m & 3) + ((kt >> 1) << 5);
    kSrc[ii] = Kb + (size_t)keym * DH + ((sl ^ (row & 7)) << 3);
    vSrc[ii] = Vb + (size_t)row * VROW + ((sl ^ (row & 7)) << 3);
  }

  // ---- prologue ----
  // 1) Q frags via regular loads, then drain so vmcnt ledger = stage DMAs only
  bf16x8 qf[2][2];       // Q as B-frags: B[k=dh][n=q=lr]
#pragma unroll
  for (int qt = 0; qt < 2; qt++) {
    const bf16* rq = Qb + (size_t)(q0 + qt * 16 + lr) * DH;
    qf[qt][0] = *(const bf16x8*)(rq + quad * 8);
    qf[qt][1] = *(const bf16x8*)(rq + 32 + quad * 8);
  }
  WAITV(0);

  // ones B-frag for l = P.1 (layout-invariant: every element is 1.0)
  bf16x8 ones;
#pragma unroll
  for (int e = 0; e < 8; e++) ones[e] = (bf16)1.0f;

  // 2) mask DMA (4 ops) then chunks 0,1,2 (4 ops each) -> 16 outstanding
#pragma unroll
  for (int ii = 0; ii < 4; ii++) {
    int g = ii * 256 + tid;
    gload16(mb + g * 4, &Mf[g * 4]);
  }
#pragma unroll
  for (int d = 0; d < 3; d++) {
    int kb = ((phase + d) & 63) * 64;
#pragma unroll
    for (int ii = 0; ii < 2; ii++) {
      int s = ii * 256 + tid;
      gload16(kSrc[ii] + (size_t)kb * DH, &Ks[d][s * 8]);
      gload16(vSrc[ii] + kb, &Vs[d][s * 8]);
    }
  }

  f32x4 O[2][4];         // O[qt][nt]: C-layout row=quad*4+r (q), col=lr (dh)
  f32x4 O_l[2];          // l accumulator: C[q][*] = sum_k P (all cols equal)
#pragma unroll
  for (int a = 0; a < 2; a++) {
#pragma unroll
    for (int c = 0; c < 4; c++) O[a][c] = f32x4{0.f, 0.f, 0.f, 0.f};
    O_l[a] = f32x4{0.f, 0.f, 0.f, 0.f};
  }

  WAITV(8);              // retires mask + chunk0; chunks 1,2 stay in flight
  __builtin_amdgcn_s_barrier();
  CFENCE;

  int cur = 0, cc = phase;
  for (int j = 0; j < 64; j++) {
    // mask C-init from LDS, PERMUTED to match K-row staging (broadcast reads)
    f32x4 mk[4];
#pragma unroll
    for (int kt = 0; kt < 4; kt++)
      mk[kt] = *(const f32x4*)&Mf[cc * 64 + ((kt >> 1) << 5) + (quad << 3) + ((kt & 1) << 2)];

    // K A-frags from swizzled LDS
    bf16x8 kr[4][2];
#pragma unroll
    for (int kt = 0; kt < 4; kt++)
#pragma unroll
      for (int kh = 0; kh < 2; kh++)
        kr[kt][kh] = *(const bf16x8*)&Ks[cur][(kt * 16 + lr) * 64 +
                                             (((kh * 4 + quad) ^ (lr & 7)) << 3)];

    // S^T = K.Q^T (permuted keys); exp2 -> in-register PV A-frags (no l adds!)
    bf16x8 pfa[2][2];
#pragma unroll
    for (int qt = 0; qt < 2; qt++) {
      f32x4 z[4];
      __builtin_amdgcn_s_setprio(1);
#pragma unroll
      for (int kt = 0; kt < 4; kt++) {
        f32x4 t = mk[kt];
        t = __builtin_amdgcn_mfma_f32_16x16x32_bf16(kr[kt][0], qf[qt][0], t, 0, 0, 0);
        t = __builtin_amdgcn_mfma_f32_16x16x32_bf16(kr[kt][1], qf[qt][1], t, 0, 0, 0);
        z[kt] = t;
      }
      __builtin_amdgcn_s_setprio(0);
#pragma unroll
      for (int kt = 0; kt < 4; kt++)
#pragma unroll
        for (int r = 0; r < 4; r++)
          pfa[qt][kt >> 1][((kt & 1) << 2) + r] = (bf16)__builtin_amdgcn_exp2f(z[kt][r]);
    }

    // V B-frags from swizzled LDS
    bf16x8 vr[4][2];
#pragma unroll
    for (int nt = 0; nt < 4; nt++)
#pragma unroll
      for (int ks = 0; ks < 2; ks++)
        vr[nt][ks] = *(const bf16x8*)&Vs[cur][(nt * 16 + lr) * 64 +
                                             (((ks * 4 + quad) ^ (lr & 7)) << 3)];

    // PV accumulate + l = P.1 on the matrix pipe
    __builtin_amdgcn_s_setprio(1);
#pragma unroll
    for (int nt = 0; nt < 4; nt++)
#pragma unroll
      for (int qt = 0; qt < 2; qt++) {
        O[qt][nt] = __builtin_amdgcn_mfma_f32_16x16x32_bf16(pfa[qt][0], vr[nt][0], O[qt][nt], 0, 0, 0);
        O[qt][nt] = __builtin_amdgcn_mfma_f32_16x16x32_bf16(pfa[qt][1], vr[nt][1], O[qt][nt], 0, 0, 0);
      }
#pragma unroll
    for (int qt = 0; qt < 2; qt++) {
      O_l[qt] = __builtin_amdgcn_mfma_f32_16x16x32_bf16(pfa[qt][0], ones, O_l[qt], 0, 0, 0);
      O_l[qt] = __builtin_amdgcn_mfma_f32_16x16x32_bf16(pfa[qt][1], ones, O_l[qt], 0, 0, 0);
    }
    __builtin_amdgcn_s_setprio(0);

    if (j < 63) {
      __builtin_amdgcn_s_barrier();   // all waves done reading buf[cur]
      CFENCE;
      if (j < 61) {                   // issue chunk cc+3 into buf[cur]
        int kb = ((cc + 3) & 63) * 64;
#pragma unroll
        for (int ii = 0; ii < 2; ii++) {
          int s = ii * 256 + tid;
          gload16(kSrc[ii] + (size_t)kb * DH, &Ks[cur][s * 8]);
          gload16(vSrc[ii] + kb, &Vs[cur][s * 8]);
        }
        WAITV(8);                     // retires chunk j+1; j+2,j+3 in flight
      } else if (j == 61) {
        WAITV(4);                     // retires chunk 62; 63 in flight
      } else {
        WAITV(0);                     // retires chunk 63
      }
      __builtin_amdgcn_s_barrier();   // chunk j+1 visible to all waves
      CFENCE;
    }
    cur = (cur == 2) ? 0 : cur + 1;
    cc = (cc + 1) & 63;
  }

  // epilogue: each lane already holds l for exactly its store rows
  // (O_l C-layout: row=quad*4+r ↔ store row; value identical across lr)
#pragma unroll
  for (int qt = 0; qt < 2; qt++) {
    float lO[4];
#pragma unroll
    for (int r = 0; r < 4; r++) lO[r] = 1.0f / O_l[qt][r];
#pragma unroll
    for (int nt = 0; nt < 4; nt++)
#pragma unroll
      for (int r = 0; r < 4; r++) {
        size_t row = (size_t)(b * T_SEQ + q0 + qt * 16 + quad * 4 + r);
        ctx[row * D_MODEL + h * DH + nt * 16 + lr] = (bf16)(O[qt][nt][r] * lO[r]);
      }
  }
}

// ---------------- kernel 4: per-tensor activation quant-dequant --------------
__global__ __launch_bounds__(256) void act_qdq(
    const float* __restrict__ pre, const unsigned int* __restrict__ amaxp,
    const int* __restrict__ flag, void* __restrict__ outv, int n)
{
  int i = (blockIdx.x * blockDim.x + threadIdx.x) * 4;
  if (i >= n) return;
  float s = fmaxf(__uint_as_float(*amaxp) / 127.0f, 1e-8f);
  float4 v = *(const float4*)(pre + i);
  float o[4] = {v.x, v.y, v.z, v.w};
#pragma unroll
  for (int r = 0; r < 4; r++) {
    float q = rintf(o[r] / s);
    q = fminf(fmaxf(q, -127.f), 127.f);
    o[r] = q * s;
  }
  if (*flag) {
    *(float4*)((float*)outv + i) = make_float4(o[0], o[1], o[2], o[3]);
  } else {
    __align__(8) bf16 ob[4] = {(bf16)o[0], (bf16)o[1], (bf16)o[2], (bf16)o[3]};
    *(uint2*)((bf16*)outv + i) = *(uint2*)ob;
  }
}

// ---------------- launch -----------------------------------------------------
extern "C" void kernel_launch(void* const* d_in, const int* in_sizes, int n_in,
                              void* d_out, int out_size, void* d_ws, size_t ws_size,
                              hipStream_t stream) {
  const void* x    = d_in[0];
  const int*  mask = (const int*)d_in[1];
  const void* Wq = d_in[2]; const void* bq = d_in[3];
  const void* Wk = d_in[4]; const void* bk = d_in[5];
  const void* Wv = d_in[6]; const void* bv = d_in[7];
  const void* Wo = d_in[8]; const void* bo = d_in[9];

  char* ws = (char*)d_ws;
  int*  flag  = (int*)(ws + 0);
  unsigned int* amax = (unsigned int*)(ws + 64);
  float* biasf = (float*)(ws + 1024);                 // 8 KB
  float* maskf = (float*)(ws + 16384);                // 32 KB
  bf16* Wt  = (bf16*)(ws + 65536);                    // 2 MB
  bf16* xb  = (bf16*)(ws + 4194304);                  // 8 MB
  bf16* Qm  = (bf16*)(ws + 12582912);                 // 8 MB head-major planes
  bf16* Km  = (bf16*)(ws + 20971520);                 // 8 MB head-major planes
  bf16* VT  = (bf16*)(ws + 29360128);                 // 8.42 MB: VTP[ch][8224]
  bf16* Cm  = (bf16*)(ws + 4194304);                  // overlays xb
  float* pre = (float*)(ws + 12582912);               // overlays Qm+Km

  hipMemsetAsync(amax, 0, 4, stream);
  detect_dtype<<<1, 64, 0, stream>>>((const unsigned short*)x, flag);
  convert_x<<<4096, 256, 0, stream>>>(x, flag, xb, M_ROWS * D_MODEL);
  prep_aux<<<8, 1024, 0, stream>>>(bq, bk, bv, bo, mask, flag, biasf, maskf);
  qdq_weights<<<512, 256, 0, stream>>>(Wq, Wk, Wv, Wo, flag, Wt);
  gemm_qkv<<<dim3(64, 12), 256, 0, stream>>>(xb, Wt, biasf, Qm, Km, VT);
  attn<<<512, 256, 0, stream>>>(Qm, Km, VT, maskf, Cm);
  gemm_o<<<dim3(128, 4), 256, 0, stream>>>(Cm, Wt + 3*262144, biasf + 1536, pre, amax);
  act_qdq<<<4096, 256, 0, stream>>>(pre, amax, flag, d_out, M_ROWS * D_MODEL);
}

// Round 11
// 215.838 us; speedup vs baseline: 1.0783x; 1.0307x over previous
//
#include <hip/hip_runtime.h>
#include <hip/hip_bf16.h>

typedef __bf16 bf16;
typedef __bf16 bf16x8 __attribute__((ext_vector_type(8)));
typedef __bf16 bf16x4v __attribute__((ext_vector_type(4)));
typedef float f32x4 __attribute__((ext_vector_type(4)));

#define D_MODEL 512
#define T_SEQ   4096
#define NH      8
#define DH      64
#define M_ROWS  8192   // B*T
#define VROW    8224   // 8192 + 32 pad tokens: V row stride 16448 B (non-pow2)
#define QK_SCALE 0.18033688011112042f   // 0.125 * log2(e), folded into Q

// async global->LDS, 16B per lane, linear LDS dest (wave base + lane*16)
__device__ __forceinline__ void gload16(const void* g, void* l) {
  __builtin_amdgcn_global_load_lds(
      (const __attribute__((address_space(1))) unsigned int*)g,
      (__attribute__((address_space(3))) unsigned int*)l, 16, 0, 0);
}

#define WAITV(N) asm volatile("s_waitcnt vmcnt(" #N ")" ::: "memory")
#define CFENCE   asm volatile("" ::: "memory")

// ---------------- kernel 0: dtype detector ----------------------------------
__global__ __launch_bounds__(64) void detect_dtype(const unsigned short* __restrict__ xr,
                                                   int* __restrict__ flag)
{
  int lane = threadIdx.x;
  int cnt = 0;
  for (int i = lane; i < 4096; i += 64) {
    unsigned short u = xr[i];
    int e = (u >> 7) & 0xFF;
    bool insane = (e >= 133) || (e > 0 && e <= 96) || (e == 0 && (u & 0x7F) != 0);
    cnt += insane ? 1 : 0;
  }
#pragma unroll
  for (int off = 32; off >= 1; off >>= 1) cnt += __shfl_xor(cnt, off);
  if (lane == 0) *flag = (cnt > 400) ? 1 : 0;   // 1 = inputs are fp32
}

// ---------------- kernel 0b: convert x to bf16 -------------------------------
__global__ __launch_bounds__(256) void convert_x(const void* __restrict__ xr,
                                                 const int* __restrict__ flag,
                                                 bf16* __restrict__ xb, int n)
{
  int i = (blockIdx.x * blockDim.x + threadIdx.x) * 4;
  if (i >= n) return;
  if (*flag) {
    float4 v = *(const float4*)((const float*)xr + i);
    __align__(8) bf16 o[4] = {(bf16)v.x, (bf16)v.y, (bf16)v.z, (bf16)v.w};
    *(uint2*)(xb + i) = *(uint2*)o;
  } else {
    *(uint2*)(xb + i) = *(const uint2*)((const bf16*)xr + i);
  }
}

// ---------------- kernel 0c: biases -> fp32, mask -> float shift -------------
__global__ __launch_bounds__(1024) void prep_aux(
    const void* b0, const void* b1, const void* b2, const void* b3,
    const int* __restrict__ mask,
    const int* __restrict__ flag, float* __restrict__ bf, float* __restrict__ mf)
{
  const void* ps[4] = {b0, b1, b2, b3};
  int fl = *flag;
  int g = blockIdx.x * 1024 + threadIdx.x;     // 0..8191
  if (g < 4 * D_MODEL) {
    int w = g >> 9, o = g & 511;
    bf[g] = fl ? ((const float*)ps[w])[o] : (float)((const bf16*)ps[w])[o];
  }
  mf[g] = mask[g] ? -16.0f : -1e30f;           // fixed-shift (exp2 domain) + mask
}

// ---------------- kernel 1: per-output-channel weight quant-dequant ----------
__global__ __launch_bounds__(256) void qdq_weights(
    const void* __restrict__ Wq, const void* __restrict__ Wk,
    const void* __restrict__ Wv, const void* __restrict__ Wo,
    const int* __restrict__ flag, bf16* __restrict__ out)
{
  int wave = threadIdx.x >> 6, lane = threadIdx.x & 63;
  int gid = blockIdx.x * 4 + wave;
  int w = gid >> 9, row = gid & 511;
  const void* W = (w == 0) ? Wq : (w == 1) ? Wk : (w == 2) ? Wv : Wo;
  int fl = *flag;
  float v[8]; float amax = 0.f;
#pragma unroll
  for (int i = 0; i < 8; i++) {
    int idx = row * D_MODEL + lane + 64 * i;
    v[i] = fl ? ((const float*)W)[idx] : (float)((const bf16*)W)[idx];
    amax = fmaxf(amax, fabsf(v[i]));
  }
#pragma unroll
  for (int off = 32; off >= 1; off >>= 1) amax = fmaxf(amax, __shfl_xor(amax, off));
  float s = fmaxf(amax / 127.0f, 1e-8f);
  bf16* dst = out + (size_t)gid * D_MODEL;
#pragma unroll
  for (int i = 0; i < 8; i++) {
    float q = rintf(v[i] / s);
    q = fminf(fmaxf(q, -127.f), 127.f);
    dst[lane + 64*i] = (bf16)(q * s);
  }
}

// ---------------- kernel 2a: fused QKV GEMM, global_load_lds staged ----------
// R11: register-round-trip staging (m93-class, ~500 TF ceiling) replaced by
// global_load_lds width-16 (m93->m97 ladder: +69%) + 2-deep counted-vmcnt
// pipeline (R8 machinery). LDS dest linear [128][32]; XOR-swizzled global
// SOURCE + swizzled ds_read (both-sides rule): slot ^= (row^(row>>2))&3 puts
// the 16-lane fragment read on 8 banks -> 2-way = free.
// Q/K written HEAD-MAJOR Qh/Kh[(b*8+h)][t][64]; V -> VTP[ch][VROW] padded.
__global__ __launch_bounds__(256) void gemm_qkv(
    const bf16* __restrict__ A, const bf16* __restrict__ W,
    const float* __restrict__ bias,
    bf16* __restrict__ Qh, bf16* __restrict__ Kh, bf16* __restrict__ VTP)
{
  __shared__ __align__(16) bf16 As[2][128 * 32];   // 16 KB
  __shared__ __align__(16) bf16 Bs[2][128 * 32];   // 16 KB

  const int tid = threadIdx.x;
  const int wave = tid >> 6, lane = tid & 63;
  const int lr = lane & 15, quad = lane >> 4;
  const int wm = (wave >> 1) * 64, wn = (wave & 1) * 64;
  const int m0 = blockIdx.x * 128, n0 = blockIdx.y * 128;
  const int sec = blockIdx.y >> 2;   // 0=Q 1=K 2=V

  // staging sources: slot s = ii*256+tid; LDS row = s>>2, slot = s&3;
  // global slot pre-swizzled by g(row) = (row^(row>>2))&3
  const bf16* aSrc[2]; const bf16* bSrc[2];
#pragma unroll
  for (int ii = 0; ii < 2; ii++) {
    int s = ii * 256 + tid, row = s >> 2, sl = s & 3;
    int g = (row ^ (row >> 2)) & 3;
    aSrc[ii] = A + (size_t)(m0 + row) * D_MODEL + ((sl ^ g) << 3);
    bSrc[ii] = W + (size_t)(n0 + row) * D_MODEL + ((sl ^ g) << 3);
  }

  f32x4 acc[4][4];
#pragma unroll
  for (int i = 0; i < 4; i++)
#pragma unroll
    for (int j = 0; j < 4; j++) acc[i][j] = f32x4{0.f, 0.f, 0.f, 0.f};

  // prologue: stage K-steps 0,1 (4 DMA ops each: 2 A + 2 B)
#pragma unroll
  for (int d = 0; d < 2; d++) {
#pragma unroll
    for (int ii = 0; ii < 2; ii++) {
      int s = ii * 256 + tid;
      gload16(aSrc[ii] + d * 32, &As[d][s * 8]);
      gload16(bSrc[ii] + d * 32, &Bs[d][s * 8]);
    }
  }
  WAITV(4);                          // step-0 tiles resident; step-1 in flight
  __builtin_amdgcn_s_barrier();
  CFENCE;

  for (int k = 0; k < 16; k++) {
    const int cur = k & 1;
    bf16x8 af[4], bfr[4];
#pragma unroll
    for (int mt = 0; mt < 4; mt++) {
      int row = wm + mt * 16 + lr;
      af[mt] = *(const bf16x8*)&As[cur][row * 32 + ((quad ^ ((row ^ (row >> 2)) & 3)) << 3)];
    }
#pragma unroll
    for (int nt = 0; nt < 4; nt++) {
      int row = wn + nt * 16 + lr;
      bfr[nt] = *(const bf16x8*)&Bs[cur][row * 32 + ((quad ^ ((row ^ (row >> 2)) & 3)) << 3)];
    }
#pragma unroll
    for (int mt = 0; mt < 4; mt++)
#pragma unroll
      for (int nt = 0; nt < 4; nt++)
        acc[mt][nt] = __builtin_amdgcn_mfma_f32_16x16x32_bf16(af[mt], bfr[nt], acc[mt][nt], 0, 0, 0);

    if (k < 15) {
      __builtin_amdgcn_s_barrier();  // all waves done reading buf[cur]
      CFENCE;
      if (k < 14) {                  // stage step k+2 into buf[cur]
#pragma unroll
        for (int ii = 0; ii < 2; ii++) {
          int s = ii * 256 + tid;
          gload16(aSrc[ii] + (k + 2) * 32, &As[cur][s * 8]);
          gload16(bSrc[ii] + (k + 2) * 32, &Bs[cur][s * 8]);
        }
        WAITV(4);                    // retires step k+1; k+2 stays in flight
      } else {
        WAITV(0);                    // retires step 15
      }
      __builtin_amdgcn_s_barrier();  // step k+1 visible to all waves
      CFENCE;
    }
  }

  const float scale = (sec == 0) ? QK_SCALE : 1.0f;
#pragma unroll
  for (int mt = 0; mt < 4; mt++) {
    int grow = m0 + wm + mt * 16 + quad * 4;
#pragma unroll
    for (int nt = 0; nt < 4; nt++) {
      int gcol = n0 + wn + nt * 16 + lr;
      float b = bias[gcol];
      if (sec == 2) {               // VTP[ch][token], packed x4, padded row
        bf16x4v pk;
#pragma unroll
        for (int r = 0; r < 4; r++) pk[r] = (bf16)(acc[mt][nt][r] + b);
        *(bf16x4v*)(VTP + (size_t)(gcol - 1024) * VROW + grow) = pk;
      } else {                      // head-major planes
        bf16* dst = (sec == 0) ? Qh : Kh;
        int c = gcol & 511;
        int hh = c >> 6, c64 = c & 63;
#pragma unroll
        for (int r = 0; r < 4; r++) {
          int row = grow + r;
          int bb = row >> 12, t = row & 4095;
          dst[((size_t)(bb * NH + hh) * T_SEQ + t) * DH + c64] =
              (bf16)((acc[mt][nt][r] + b) * scale);
        }
      }
    }
  }
}

// ---------------- kernel 2b: O-proj GEMM, global_load_lds staged -------------
__global__ __launch_bounds__(256) void gemm_o(
    const bf16* __restrict__ A, const bf16* __restrict__ W,
    const float* __restrict__ bias,
    float* __restrict__ Cf, unsigned int* __restrict__ amaxp)
{
  __shared__ __align__(16) bf16 As[2][64 * 32];    // 8 KB
  __shared__ __align__(16) bf16 Bs[2][128 * 32];   // 16 KB
  __shared__ float wred[4];

  const int tid = threadIdx.x;
  const int wave = tid >> 6, lane = tid & 63;
  const int lr = lane & 15, quad = lane >> 4;
  const int wm = (wave >> 1) * 32, wn = (wave & 1) * 64;
  const int m0 = blockIdx.x * 64, n0 = blockIdx.y * 128;

  const bf16* aSrc; const bf16* bSrc[2];
  {
    int s = tid, row = s >> 2, sl = s & 3;
    int g = (row ^ (row >> 2)) & 3;
    aSrc = A + (size_t)(m0 + row) * D_MODEL + ((sl ^ g) << 3);
  }
#pragma unroll
  for (int ii = 0; ii < 2; ii++) {
    int s = ii * 256 + tid, row = s >> 2, sl = s & 3;
    int g = (row ^ (row >> 2)) & 3;
    bSrc[ii] = W + (size_t)(n0 + row) * D_MODEL + ((sl ^ g) << 3);
  }

  f32x4 acc[2][4];
#pragma unroll
  for (int i = 0; i < 2; i++)
#pragma unroll
    for (int j = 0; j < 4; j++) acc[i][j] = f32x4{0.f, 0.f, 0.f, 0.f};

  // prologue: stage K-steps 0,1 (3 DMA ops each: 1 A + 2 B)
#pragma unroll
  for (int d = 0; d < 2; d++) {
    gload16(aSrc + d * 32, &As[d][tid * 8]);
#pragma unroll
    for (int ii = 0; ii < 2; ii++) {
      int s = ii * 256 + tid;
      gload16(bSrc[ii] + d * 32, &Bs[d][s * 8]);
    }
  }
  WAITV(3);
  __builtin_amdgcn_s_barrier();
  CFENCE;

  for (int k = 0; k < 16; k++) {
    const int cur = k & 1;
    bf16x8 af[2], bfr[4];
#pragma unroll
    for (int mt = 0; mt < 2; mt++) {
      int row = wm + mt * 16 + lr;
      af[mt] = *(const bf16x8*)&As[cur][row * 32 + ((quad ^ ((row ^ (row >> 2)) & 3)) << 3)];
    }
#pragma unroll
    for (int nt = 0; nt < 4; nt++) {
      int row = wn + nt * 16 + lr;
      bfr[nt] = *(const bf16x8*)&Bs[cur][row * 32 + ((quad ^ ((row ^ (row >> 2)) & 3)) << 3)];
    }
#pragma unroll
    for (int mt = 0; mt < 2; mt++)
#pragma unroll
      for (int nt = 0; nt < 4; nt++)
        acc[mt][nt] = __builtin_amdgcn_mfma_f32_16x16x32_bf16(af[mt], bfr[nt], acc[mt][nt], 0, 0, 0);

    if (k < 15) {
      __builtin_amdgcn_s_barrier();
      CFENCE;
      if (k < 14) {
        gload16(aSrc + (k + 2) * 32, &As[cur][tid * 8]);
#pragma unroll
        for (int ii = 0; ii < 2; ii++) {
          int s = ii * 256 + tid;
          gload16(bSrc[ii] + (k + 2) * 32, &Bs[cur][s * 8]);
        }
        WAITV(3);
      } else {
        WAITV(0);
      }
      __builtin_amdgcn_s_barrier();
      CFENCE;
    }
  }

  float lmax = 0.f;
#pragma unroll
  for (int mt = 0; mt < 2; mt++) {
    int grow = m0 + wm + mt * 16 + quad * 4;
#pragma unroll
    for (int nt = 0; nt < 4; nt++) {
      int gcol = n0 + wn + nt * 16 + lr;
      float b = bias[gcol];
#pragma unroll
      for (int r = 0; r < 4; r++) {
        float v = acc[mt][nt][r] + b;
        Cf[(size_t)(grow + r) * D_MODEL + gcol] = v;
        lmax = fmaxf(lmax, fabsf(v));
      }
    }
  }
#pragma unroll
  for (int off = 32; off >= 1; off >>= 1) lmax = fmaxf(lmax, __shfl_xor(lmax, off));
  if (lane == 0) wred[wave] = lmax;
  __syncthreads();
  if (tid == 0) {
    float m = fmaxf(fmaxf(wred[0], wred[1]), fmaxf(wred[2], wred[3]));
    atomicMax(amaxp, __float_as_uint(m));
  }
}

// ---------------- kernel 3: flash attention (R8 variant, best measured) ------
// 512 blocks x 256 thr (4 waves), 2 blocks/CU. Waves split q (32 rows each),
// share the staged key stream; P fully in-register via permuted-K staging;
// counted-vmcnt 3-deep DMA pipeline with raw s_barrier.
__global__ __launch_bounds__(256, 2) void attn(
    const bf16* __restrict__ Q, const bf16* __restrict__ K, const bf16* __restrict__ VT,
    const float* __restrict__ maskf, bf16* __restrict__ ctx)
{
  __shared__ __align__(16) bf16 Ks[3][64 * 64];          // 24 KB
  __shared__ __align__(16) bf16 Vs[3][64 * 64];          // 24 KB
  __shared__ __align__(16) float Mf[T_SEQ];              // 16 KB  (64 KB total)

  const int tid = threadIdx.x;
  const int wave = tid >> 6, lane = tid & 63;
  const int lr = lane & 15, quad = lane >> 4;
  const int i = blockIdx.x;
  const int bh = (i & 7) * 2 + ((i >> 3) & 1);
  const int qb = i >> 4;                    // 0..31
  const int b = bh >> 3, h = bh & 7;
  const int q0 = qb * 128 + wave * 32;

  const bf16* Qb = Q + (size_t)bh * T_SEQ * DH;
  const bf16* Kb = K + (size_t)bh * T_SEQ * DH;
  const bf16* Vb = VT + (size_t)(h * DH) * VROW + (size_t)b * T_SEQ;
  const float* mb = maskf + b * T_SEQ;

  const int phase = (qb * 2) & 63;

  const bf16* kSrc[2]; const bf16* vSrc[2];
#pragma unroll
  for (int ii = 0; ii < 2; ii++) {
    int s = ii * 256 + tid, row = s >> 3, sl = s & 7;
    int kt = row >> 4, m = row & 15;
    int keym = ((m >> 2) << 3) + ((kt & 1) << 2) + (m & 3) + ((kt >> 1) << 5);
    kSrc[ii] = Kb + (size_t)keym * DH + ((sl ^ (row & 7)) << 3);
    vSrc[ii] = Vb + (size_t)row * VROW + ((sl ^ (row & 7)) << 3);
  }

  bf16x8 qf[2][2];
#pragma unroll
  for (int qt = 0; qt < 2; qt++) {
    const bf16* rq = Qb + (size_t)(q0 + qt * 16 + lr) * DH;
    qf[qt][0] = *(const bf16x8*)(rq + quad * 8);
    qf[qt][1] = *(const bf16x8*)(rq + 32 + quad * 8);
  }
  WAITV(0);

#pragma unroll
  for (int ii = 0; ii < 4; ii++) {
    int g = ii * 256 + tid;
    gload16(mb + g * 4, &Mf[g * 4]);
  }
#pragma unroll
  for (int d = 0; d < 3; d++) {
    int kb = ((phase + d) & 63) * 64;
#pragma unroll
    for (int ii = 0; ii < 2; ii++) {
      int s = ii * 256 + tid;
      gload16(kSrc[ii] + (size_t)kb * DH, &Ks[d][s * 8]);
      gload16(vSrc[ii] + kb, &Vs[d][s * 8]);
    }
  }

  f32x4 O[2][4];
#pragma unroll
  for (int a = 0; a < 2; a++)
#pragma unroll
    for (int c = 0; c < 4; c++) O[a][c] = f32x4{0.f, 0.f, 0.f, 0.f};
  float lacc[2] = {0.f, 0.f};

  WAITV(8);
  __builtin_amdgcn_s_barrier();
  CFENCE;

  int cur = 0, cc = phase;
  for (int j = 0; j < 64; j++) {
    f32x4 mk[4];
#pragma unroll
    for (int kt = 0; kt < 4; kt++)
      mk[kt] = *(const f32x4*)&Mf[cc * 64 + ((kt >> 1) << 5) + (quad << 3) + ((kt & 1) << 2)];

    bf16x8 kr[4][2];
#pragma unroll
    for (int kt = 0; kt < 4; kt++)
#pragma unroll
      for (int kh = 0; kh < 2; kh++)
        kr[kt][kh] = *(const bf16x8*)&Ks[cur][(kt * 16 + lr) * 64 +
                                             (((kh * 4 + quad) ^ (lr & 7)) << 3)];

    bf16x8 pfa[2][2];
#pragma unroll
    for (int qt = 0; qt < 2; qt++) {
      f32x4 z[4];
#pragma unroll
      for (int kt = 0; kt < 4; kt++) {
        f32x4 t = mk[kt];
        t = __builtin_amdgcn_mfma_f32_16x16x32_bf16(kr[kt][0], qf[qt][0], t, 0, 0, 0);
        t = __builtin_amdgcn_mfma_f32_16x16x32_bf16(kr[kt][1], qf[qt][1], t, 0, 0, 0);
        z[kt] = t;
      }
      float la = lacc[qt];
#pragma unroll
      for (int kt = 0; kt < 4; kt++) {
#pragma unroll
        for (int r = 0; r < 4; r++) {
          float p = __builtin_amdgcn_exp2f(z[kt][r]);
          la += p;
          pfa[qt][kt >> 1][((kt & 1) << 2) + r] = (bf16)p;
        }
      }
      lacc[qt] = la;
    }

    bf16x8 vr[4][2];
#pragma unroll
    for (int nt = 0; nt < 4; nt++)
#pragma unroll
      for (int ks = 0; ks < 2; ks++)
        vr[nt][ks] = *(const bf16x8*)&Vs[cur][(nt * 16 + lr) * 64 +
                                             (((ks * 4 + quad) ^ (lr & 7)) << 3)];

#pragma unroll
    for (int nt = 0; nt < 4; nt++)
#pragma unroll
      for (int qt = 0; qt < 2; qt++) {
        O[qt][nt] = __builtin_amdgcn_mfma_f32_16x16x32_bf16(pfa[qt][0], vr[nt][0], O[qt][nt], 0, 0, 0);
        O[qt][nt] = __builtin_amdgcn_mfma_f32_16x16x32_bf16(pfa[qt][1], vr[nt][1], O[qt][nt], 0, 0, 0);
      }

    if (j < 63) {
      __builtin_amdgcn_s_barrier();
      CFENCE;
      if (j < 61) {
        int kb = ((cc + 3) & 63) * 64;
#pragma unroll
        for (int ii = 0; ii < 2; ii++) {
          int s = ii * 256 + tid;
          gload16(kSrc[ii] + (size_t)kb * DH, &Ks[cur][s * 8]);
          gload16(vSrc[ii] + kb, &Vs[cur][s * 8]);
        }
        WAITV(8);
      } else if (j == 61) {
        WAITV(4);
      } else {
        WAITV(0);
      }
      __builtin_amdgcn_s_barrier();
      CFENCE;
    }
    cur = (cur == 2) ? 0 : cur + 1;
    cc = (cc + 1) & 63;
  }

#pragma unroll
  for (int qt = 0; qt < 2; qt++) {
    float ls = lacc[qt];
    ls += __shfl_xor(ls, 16);
    ls += __shfl_xor(ls, 32);
    float linv = 1.0f / ls;
    float lO[4];
#pragma unroll
    for (int r = 0; r < 4; r++) lO[r] = __shfl(linv, quad * 4 + r);
#pragma unroll
    for (int nt = 0; nt < 4; nt++)
#pragma unroll
      for (int r = 0; r < 4; r++) {
        size_t row = (size_t)(b * T_SEQ + q0 + qt * 16 + quad * 4 + r);
        ctx[row * D_MODEL + h * DH + nt * 16 + lr] = (bf16)(O[qt][nt][r] * lO[r]);
      }
  }
}

// ---------------- kernel 4: per-tensor activation quant-dequant --------------
__global__ __launch_bounds__(256) void act_qdq(
    const float* __restrict__ pre, const unsigned int* __restrict__ amaxp,
    const int* __restrict__ flag, void* __restrict__ outv, int n)
{
  int i = (blockIdx.x * blockDim.x + threadIdx.x) * 4;
  if (i >= n) return;
  float s = fmaxf(__uint_as_float(*amaxp) / 127.0f, 1e-8f);
  float4 v = *(const float4*)(pre + i);
  float o[4] = {v.x, v.y, v.z, v.w};
#pragma unroll
  for (int r = 0; r < 4; r++) {
    float q = rintf(o[r] / s);
    q = fminf(fmaxf(q, -127.f), 127.f);
    o[r] = q * s;
  }
  if (*flag) {
    *(float4*)((float*)outv + i) = make_float4(o[0], o[1], o[2], o[3]);
  } else {
    __align__(8) bf16 ob[4] = {(bf16)o[0], (bf16)o[1], (bf16)o[2], (bf16)o[3]};
    *(uint2*)((bf16*)outv + i) = *(uint2*)ob;
  }
}

// ---------------- launch -----------------------------------------------------
extern "C" void kernel_launch(void* const* d_in, const int* in_sizes, int n_in,
                              void* d_out, int out_size, void* d_ws, size_t ws_size,
                              hipStream_t stream) {
  const void* x    = d_in[0];
  const int*  mask = (const int*)d_in[1];
  const void* Wq = d_in[2]; const void* bq = d_in[3];
  const void* Wk = d_in[4]; const void* bk = d_in[5];
  const void* Wv = d_in[6]; const void* bv = d_in[7];
  const void* Wo = d_in[8]; const void* bo = d_in[9];

  char* ws = (char*)d_ws;
  int*  flag  = (int*)(ws + 0);
  unsigned int* amax = (unsigned int*)(ws + 64);
  float* biasf = (float*)(ws + 1024);                 // 8 KB
  float* maskf = (float*)(ws + 16384);                // 32 KB
  bf16* Wt  = (bf16*)(ws + 65536);                    // 2 MB
  bf16* xb  = (bf16*)(ws + 4194304);                  // 8 MB
  bf16* Qm  = (bf16*)(ws + 12582912);                 // 8 MB head-major planes
  bf16* Km  = (bf16*)(ws + 20971520);                 // 8 MB head-major planes
  bf16* VT  = (bf16*)(ws + 29360128);                 // 8.42 MB: VTP[ch][8224]
  bf16* Cm  = (bf16*)(ws + 4194304);                  // overlays xb
  float* pre = (float*)(ws + 12582912);               // overlays Qm+Km

  hipMemsetAsync(amax, 0, 4, stream);
  detect_dtype<<<1, 64, 0, stream>>>((const unsigned short*)x, flag);
  convert_x<<<4096, 256, 0, stream>>>(x, flag, xb, M_ROWS * D_MODEL);
  prep_aux<<<8, 1024, 0, stream>>>(bq, bk, bv, bo, mask, flag, biasf, maskf);
  qdq_weights<<<512, 256, 0, stream>>>(Wq, Wk, Wv, Wo, flag, Wt);
  gemm_qkv<<<dim3(64, 12), 256, 0, stream>>>(xb, Wt, biasf, Qm, Km, VT);
  attn<<<512, 256, 0, stream>>>(Qm, Km, VT, maskf, Cm);
  gemm_o<<<dim3(128, 4), 256, 0, stream>>>(Cm, Wt + 3*262144, biasf + 1536, pre, amax);
  act_qdq<<<4096, 256, 0, stream>>>(pre, amax, flag, d_out, M_ROWS * D_MODEL);
}